// Round 6
// baseline (187.055 us; speedup 1.0000x reference)
//
#include <hip/hip_runtime.h>

// WellTemparedMetaDynamics: B=32, H=200000, D=8
// eng[b]    = sum_h hgt_h[b,h] * exp(-0.5 * sum_d (cen-col)^2 * prc_h)
// new_hgt[b]= hgt * exp(-eng[b] / (kbt[b]*(gam-1)))
// outputs: cen_out (B,H+1,D) | prc_out (B,H+1,D) | hgt_out (B,H+1)  (flat concat)
//
// Ladder: R0 186us hill-per-thread | R2 nt-stores 213us (revert) | R4 store-align
// shift neutral -> not RFO. R5: pair-lane FLAT layout — every cen/prc load and
// store is a contiguous 1024B wave access (memcpy shape, 8 full lines/instr)
// instead of stride-32B half-line accesses (16 half lines/instr). Energy via
// __shfl_xor(s,1) pair-combine; hgt copied coalesced + re-read L1-hot.

#define BB 32
#define HH 200000
#define DD 8
#define BLK 256
#define IT 16
#define CHUNK (BLK * IT)          // 4096 float4 per block
#define F4B (HH * 2)              // 400000 float4 per batch (cen/prc)

typedef float f32x4 __attribute__((ext_vector_type(4)));

__global__ __launch_bounds__(BLK) void wtmtd_main(
    const float* __restrict__ col,
    const float* __restrict__ cen,
    const float* __restrict__ prc_h,
    const float* __restrict__ hgt_h,
    float* __restrict__ cen_out,
    float* __restrict__ prc_out,
    float* __restrict__ hgt_out,
    float* __restrict__ partials)
{
    const int b = blockIdx.y;
    const int t = threadIdx.x;

    const size_t hIn  = (size_t)b * HH;
    const size_t hOut = (size_t)b * (HH + 1);

    const f32x4* cen4 = (const f32x4*)cen   + (size_t)b * F4B;
    const f32x4* prc4 = (const f32x4*)prc_h + (size_t)b * F4B;
    f32x4* co = (f32x4*)cen_out + (size_t)b * (F4B + 2);
    f32x4* po = (f32x4*)prc_out + (size_t)b * (F4B + 2);

    // lane-constant: col half matching this lane's parity, and even-lane mask
    const f32x4* colv = (const f32x4*)(col + (size_t)b * DD);
    const f32x4 c_my  = colv[t & 1];
    const float mask0 = (t & 1) ? 0.0f : 1.0f;

    const int base  = blockIdx.x * CHUNK;   // float4 index within batch
    const int hbase = base >> 1;            // hill index within batch

    // ---- hgt copy: scalar but fully coalesced (256B/wave-instr, full lines);
    // also warms L1/L2 for the energy re-reads below.
    #pragma unroll
    for (int i = 0; i < IT / 2; ++i) {      // 8 * 256 = 2048 hills per block
        const int h = hbase + i * BLK + t;
        if (h < HH) hgt_out[hOut + h] = hgt_h[hIn + h];
    }

    float local = 0.0f;
    const bool full = (base + CHUNK) <= F4B;   // block-uniform

    if (full) {
        #pragma unroll 4
        for (int i = 0; i < IT; ++i) {
            const int idx = base + i * BLK + t;
            const f32x4 v = cen4[idx];
            const f32x4 p = prc4[idx];
            const float hh = hgt_h[hIn + (idx >> 1)];   // L1-hot

            const f32x4 d = v - c_my;
            float s = d.x*d.x*p.x + d.y*d.y*p.y + d.z*d.z*p.z + d.w*d.w*p.w;
            s += __shfl_xor(s, 1);                       // pair-combine halves
            local += mask0 * hh * __expf(-0.5f * s);

            co[idx] = v;
            po[idx] = p;
        }
    } else {
        #pragma unroll 4
        for (int i = 0; i < IT; ++i) {
            const int idx = base + i * BLK + t;
            if (idx < F4B) {                 // pairs stay together (F4B even)
                const f32x4 v = cen4[idx];
                const f32x4 p = prc4[idx];
                const float hh = hgt_h[hIn + (idx >> 1)];

                const f32x4 d = v - c_my;
                float s = d.x*d.x*p.x + d.y*d.y*p.y + d.z*d.z*p.z + d.w*d.w*p.w;
                s += __shfl_xor(s, 1);
                local += mask0 * hh * __expf(-0.5f * s);

                co[idx] = v;
                po[idx] = p;
            }
        }
    }

    // wave64 shuffle reduce, then cross-wave via LDS
    #pragma unroll
    for (int off = 32; off > 0; off >>= 1)
        local += __shfl_down(local, off);

    __shared__ float sred[BLK / 64];
    const int lane = t & 63;
    const int wv   = t >> 6;
    if (lane == 0) sred[wv] = local;
    __syncthreads();
    if (t == 0) {
        float s = 0.0f;
        #pragma unroll
        for (int i = 0; i < BLK / 64; ++i) s += sred[i];
        partials[(size_t)b * gridDim.x + blockIdx.x] = s;
    }
}

// Final: reduce partials (fixed order -> deterministic), compute new hill,
// write the appended slot H for all three outputs.
__global__ __launch_bounds__(64) void wtmtd_fin(
    const float* __restrict__ partials, int nblk,
    const float* __restrict__ col,
    const float* __restrict__ kbt,
    const float* __restrict__ prc,
    const float* __restrict__ hgt,
    const float* __restrict__ gam,
    float* __restrict__ cen_out,
    float* __restrict__ prc_out,
    float* __restrict__ hgt_out)
{
    const int b = blockIdx.x;

    float s = 0.0f;
    for (int i = threadIdx.x; i < nblk; i += 64)
        s += partials[(size_t)b * nblk + i];
    #pragma unroll
    for (int off = 32; off > 0; off >>= 1)
        s += __shfl_down(s, off);
    s = __shfl(s, 0);   // broadcast eng[b]

    const float det = kbt[b] * (gam[0] - 1.0f);
    const float new_hgt = hgt[0] * expf(-s / det);

    const size_t outBase = (size_t)b * (HH + 1);
    if (threadIdx.x < DD) {
        cen_out[(outBase + HH) * DD + threadIdx.x] = col[(size_t)b * DD + threadIdx.x];
        prc_out[(outBase + HH) * DD + threadIdx.x] = prc[threadIdx.x];
    }
    if (threadIdx.x == 0)
        hgt_out[outBase + HH] = new_hgt;
}

extern "C" void kernel_launch(void* const* d_in, const int* in_sizes, int n_in,
                              void* d_out, int out_size, void* d_ws, size_t ws_size,
                              hipStream_t stream) {
    const float* col   = (const float*)d_in[0];
    const float* cen   = (const float*)d_in[1];
    const float* prc_h = (const float*)d_in[2];
    const float* hgt_h = (const float*)d_in[3];
    const float* kbt   = (const float*)d_in[4];
    const float* prc   = (const float*)d_in[5];
    const float* hgt   = (const float*)d_in[6];
    const float* gam   = (const float*)d_in[7];

    float* cen_out = (float*)d_out;
    float* prc_out = cen_out + (size_t)BB * (HH + 1) * DD;
    float* hgt_out = prc_out + (size_t)BB * (HH + 1) * DD;

    float* partials = (float*)d_ws;

    const int nblkx = (F4B + CHUNK - 1) / CHUNK;  // 98
    dim3 grid(nblkx, BB);

    wtmtd_main<<<grid, BLK, 0, stream>>>(col, cen, prc_h, hgt_h,
                                         cen_out, prc_out, hgt_out, partials);
    wtmtd_fin<<<BB, 64, 0, stream>>>(partials, nblkx, col, kbt, prc, hgt, gam,
                                     cen_out, prc_out, hgt_out);
}

// Round 7
// 168.820 us; speedup vs baseline: 1.1080x; 1.1080x over previous
//
#include <hip/hip_runtime.h>

// WellTemparedMetaDynamics: B=32, H=200000, D=8
// eng[b]    = sum_h hgt_h[b,h] * exp(-0.5 * sum_d (cen-col)^2 * prc_h)
// new_hgt[b]= hgt * exp(-eng[b] / (kbt[b]*(gam-1)))
// outputs: cen_out (B,H+1,D) | prc_out (B,H+1,D) | hgt_out (B,H+1)  (flat concat)
//
// Ladder: R0 186 | R2 nt-stores 213 (revert) | R3 __expf 181 | R4 store-align
// neutral | R5 flat+shfl 187 (neutral). Access shape is NOT the limiter.
// R6: deep register burst — 16 independent 16B loads/thread in flight, then
// 16-deep store burst (MLP + same-direction HBM bursts). Energy via
// __shfl_xor(s,1) pair-combine as in R5.

#define BB 32
#define HH 200000
#define DD 8
#define BLK 256
#define IT 16
#define KB 8                      // burst depth (pairs per burst)
#define CHUNK (BLK * IT)          // 4096 float4 per block
#define F4B (HH * 2)              // 400000 float4 per batch (cen/prc)

typedef float f32x4 __attribute__((ext_vector_type(4)));

__global__ __launch_bounds__(BLK) void wtmtd_main(
    const float* __restrict__ col,
    const float* __restrict__ cen,
    const float* __restrict__ prc_h,
    const float* __restrict__ hgt_h,
    float* __restrict__ cen_out,
    float* __restrict__ prc_out,
    float* __restrict__ hgt_out,
    float* __restrict__ partials)
{
    const int b = blockIdx.y;
    const int t = threadIdx.x;

    const size_t hIn  = (size_t)b * HH;
    const size_t hOut = (size_t)b * (HH + 1);

    const f32x4* cen4 = (const f32x4*)cen   + (size_t)b * F4B;
    const f32x4* prc4 = (const f32x4*)prc_h + (size_t)b * F4B;
    f32x4* co = (f32x4*)cen_out + (size_t)b * (F4B + 2);
    f32x4* po = (f32x4*)prc_out + (size_t)b * (F4B + 2);

    // lane-constant: col half matching this lane's parity, and even-lane mask
    const f32x4* colv = (const f32x4*)(col + (size_t)b * DD);
    const f32x4 c_my  = colv[t & 1];
    const float mask0 = (t & 1) ? 0.0f : 1.0f;

    const int base  = blockIdx.x * CHUNK;   // float4 index within batch
    const int hbase = base >> 1;            // hill index within batch

    // hgt copy: fully coalesced scalar (256B/wave-instr); warms L1 for re-reads.
    #pragma unroll
    for (int i = 0; i < IT / 2; ++i) {      // 8 * 256 = 2048 hills per block
        const int h = hbase + i * BLK + t;
        if (h < HH) hgt_out[hOut + h] = hgt_h[hIn + h];
    }

    float local = 0.0f;
    const bool full = (base + CHUNK) <= F4B;   // block-uniform

    if (full) {
        #pragma unroll
        for (int half = 0; half < IT / KB; ++half) {
            f32x4 v[KB], p[KB];
            // ---- 16 independent loads in flight (16KB/wave read burst)
            #pragma unroll
            for (int j = 0; j < KB; ++j)
                v[j] = cen4[base + (half * KB + j) * BLK + t];
            #pragma unroll
            for (int j = 0; j < KB; ++j)
                p[j] = prc4[base + (half * KB + j) * BLK + t];

            // ---- energy for KB pairs
            #pragma unroll
            for (int j = 0; j < KB; ++j) {
                const int idx = base + (half * KB + j) * BLK + t;
                const float hh = hgt_h[hIn + (idx >> 1)];   // L1-hot
                const f32x4 d = v[j] - c_my;
                float s = d.x*d.x*p[j].x + d.y*d.y*p[j].y
                        + d.z*d.z*p[j].z + d.w*d.w*p[j].w;
                s += __shfl_xor(s, 1);                      // pair-combine halves
                local += mask0 * hh * __expf(-0.5f * s);
            }

            // ---- 16-deep store burst (16KB/wave write burst)
            #pragma unroll
            for (int j = 0; j < KB; ++j)
                co[base + (half * KB + j) * BLK + t] = v[j];
            #pragma unroll
            for (int j = 0; j < KB; ++j)
                po[base + (half * KB + j) * BLK + t] = p[j];
        }
    } else {
        #pragma unroll 4
        for (int i = 0; i < IT; ++i) {
            const int idx = base + i * BLK + t;
            if (idx < F4B) {                 // pairs stay together (F4B even)
                const f32x4 v = cen4[idx];
                const f32x4 p = prc4[idx];
                const float hh = hgt_h[hIn + (idx >> 1)];

                const f32x4 d = v - c_my;
                float s = d.x*d.x*p.x + d.y*d.y*p.y + d.z*d.z*p.z + d.w*d.w*p.w;
                s += __shfl_xor(s, 1);
                local += mask0 * hh * __expf(-0.5f * s);

                co[idx] = v;
                po[idx] = p;
            }
        }
    }

    // wave64 shuffle reduce, then cross-wave via LDS
    #pragma unroll
    for (int off = 32; off > 0; off >>= 1)
        local += __shfl_down(local, off);

    __shared__ float sred[BLK / 64];
    const int lane = t & 63;
    const int wv   = t >> 6;
    if (lane == 0) sred[wv] = local;
    __syncthreads();
    if (t == 0) {
        float s = 0.0f;
        #pragma unroll
        for (int i = 0; i < BLK / 64; ++i) s += sred[i];
        partials[(size_t)b * gridDim.x + blockIdx.x] = s;
    }
}

// Final: reduce partials (fixed order -> deterministic), compute new hill,
// write the appended slot H for all three outputs.
__global__ __launch_bounds__(64) void wtmtd_fin(
    const float* __restrict__ partials, int nblk,
    const float* __restrict__ col,
    const float* __restrict__ kbt,
    const float* __restrict__ prc,
    const float* __restrict__ hgt,
    const float* __restrict__ gam,
    float* __restrict__ cen_out,
    float* __restrict__ prc_out,
    float* __restrict__ hgt_out)
{
    const int b = blockIdx.x;

    float s = 0.0f;
    for (int i = threadIdx.x; i < nblk; i += 64)
        s += partials[(size_t)b * nblk + i];
    #pragma unroll
    for (int off = 32; off > 0; off >>= 1)
        s += __shfl_down(s, off);
    s = __shfl(s, 0);   // broadcast eng[b]

    const float det = kbt[b] * (gam[0] - 1.0f);
    const float new_hgt = hgt[0] * expf(-s / det);

    const size_t outBase = (size_t)b * (HH + 1);
    if (threadIdx.x < DD) {
        cen_out[(outBase + HH) * DD + threadIdx.x] = col[(size_t)b * DD + threadIdx.x];
        prc_out[(outBase + HH) * DD + threadIdx.x] = prc[threadIdx.x];
    }
    if (threadIdx.x == 0)
        hgt_out[outBase + HH] = new_hgt;
}

extern "C" void kernel_launch(void* const* d_in, const int* in_sizes, int n_in,
                              void* d_out, int out_size, void* d_ws, size_t ws_size,
                              hipStream_t stream) {
    const float* col   = (const float*)d_in[0];
    const float* cen   = (const float*)d_in[1];
    const float* prc_h = (const float*)d_in[2];
    const float* hgt_h = (const float*)d_in[3];
    const float* kbt   = (const float*)d_in[4];
    const float* prc   = (const float*)d_in[5];
    const float* hgt   = (const float*)d_in[6];
    const float* gam   = (const float*)d_in[7];

    float* cen_out = (float*)d_out;
    float* prc_out = cen_out + (size_t)BB * (HH + 1) * DD;
    float* hgt_out = prc_out + (size_t)BB * (HH + 1) * DD;

    float* partials = (float*)d_ws;

    const int nblkx = (F4B + CHUNK - 1) / CHUNK;  // 98
    dim3 grid(nblkx, BB);

    wtmtd_main<<<grid, BLK, 0, stream>>>(col, cen, prc_h, hgt_h,
                                         cen_out, prc_out, hgt_out, partials);
    wtmtd_fin<<<BB, 64, 0, stream>>>(partials, nblkx, col, kbt, prc, hgt, gam,
                                     cen_out, prc_out, hgt_out);
}